// Round 2
// baseline (807.979 us; speedup 1.0000x reference)
//
#include <hip/hip_runtime.h>
#include <math.h>
#include <stdint.h>

// ---------------------------------------------------------------------------
// Muskingum-Cunge tree routing, spatially-pipelined persistent kernel, v12.
//
// v11 result: 755 -> 661 us (parallel tag-reload worked, partial). Residual
// theory: VGPR_Count=80 < 96 regs needed for the B=16 ping-pong banks alone
// => the lat/pend banks live in SCRATCH (the body-lambda took them as raw
// pointers, defeating SROA; and __launch_bounds__(256) let the RA spill for
// occupancy this 1-wave/SIMD kernel doesn't want). Scratch loads of
// latC[j]/pendC[j] sit directly on the serial Q-recurrence chain
// (~100+cy each per step).
//
// v12 change (arithmetic untouched, bit-identical results):
//   (1) body lambda -> textual MC_BODY macro: all bank accesses are
//       constant-index accesses on plain local arrays -> guaranteed SROA
//       promotion to VGPRs.
//   (2) __launch_bounds__(256, 1): allocator free to use ~256 VGPRs
//       (kernel is intentionally 1 wave/SIMD; occupancy is irrelevant).
//
// Protocol unchanged from v11: per-level persistent blocks, batched ring
// handoff, tagged 8-byte relaxed agent-scope atomics, flat mismatch scan +
// parallel reload + spin backstop, next-batch register prefetch, per-wave
// progress counters, DPP pair_sum, 2x-unrolled ping-pong batch loop.
// ---------------------------------------------------------------------------

#define N_LEVELS   14
#define T_STEPS    2048
#define NR_TOTAL   16383
#define DT_SUB_F   21600.0f
#define EPS_F      1e-6f
#define NBLOCKS    71
#define CTR_STRIDE 8             // ints per wave counter (32 B apart)
#define RING_BYTE_OFF 16384

__device__ __constant__ int kSize[N_LEVELS] = {8192,4096,2048,1024,512,256,128,64,32,16,8,4,2,1};
__device__ __constant__ int kEpb [N_LEVELS] = {256,256,256,256,256,256,128,64,32,16,8,4,2,1};
__device__ __constant__ int kBlkStart[N_LEVELS+1] = {0,32,48,56,60,62,63,64,65,66,67,68,69,70,71};
__device__ __constant__ int kOffL[N_LEVELS] = {0,8192,12288,14336,15360,15872,16128,16256,16320,16352,16368,16376,16380,16382};
// pair-sum entries before level l
__device__ __constant__ int kOffH[N_LEVELS-1] = {0,4096,6144,7168,7680,7936,8064,8128,8160,8176,8184,8188,8190};

#if __has_builtin(__builtin_amdgcn_exp2f)
#define FAST_EXP2(x) __builtin_amdgcn_exp2f(x)
#else
#define FAST_EXP2(x) exp2f(x)
#endif
#if __has_builtin(__builtin_amdgcn_logf)
#define FAST_LOG2(x) __builtin_amdgcn_logf(x)
#else
#define FAST_LOG2(x) log2f(x)
#endif
#if __has_builtin(__builtin_amdgcn_rcpf)
#define FAST_RCP(x) __builtin_amdgcn_rcpf(x)
#else
#define FAST_RCP(x) (1.0f/(x))
#endif

// pair sum of lanes (2k,2k+1) via DPP quad_perm [1,0,3,2]: pure VALU, no LDS.
__device__ __forceinline__ float pair_sum(float x) {
    int yi = __builtin_amdgcn_update_dpp(0, __float_as_int(x),
                                         0xB1 /*quad_perm 1,0,3,2*/,
                                         0xF, 0xF, true);
    return x + __int_as_float(yi);
}

#define ATOMIC_LD_RLX(p)   __hip_atomic_load((p), __ATOMIC_RELAXED, __HIP_MEMORY_SCOPE_AGENT)
#define ATOMIC_ST_RLX(p,v) __hip_atomic_store((p), (v), __ATOMIC_RELAXED, __HIP_MEMORY_SCOPE_AGENT)

// ---------------------------------------------------------------------------
// One batch body. Textual macro (NOT a lambda/function): latC/pendC/latN/pendN
// substitute to the actual array names so every access is a constant-index
// access on a plain local array -> SROA promotes all banks to VGPRs.
// ---------------------------------------------------------------------------
#define MC_BODY(BI, latC, pendC, latN, pendN)                                  \
  {                                                                            \
    const int bi = (BI);                                                       \
    const int tb = bi * B;                                                     \
                                                                               \
    /* ---- prefetch NEXT batch into the other bank ---- */                    \
    if (bi + 1 < NB) {                                                         \
      _Pragma("unroll")                                                        \
      for (int j = 0; j < B; ++j)                                              \
        latN[j] = lat[(size_t)(tb + B + j) * NR_TOTAL + rr];                   \
      if (hasProd && validT) {                                                 \
        const unsigned long long* upN =                                        \
            ringUp + (size_t)((bi + 1) & sBm1) * upSlotSz + e;                 \
        _Pragma("unroll")                                                      \
        for (int j = 0; j < B; ++j)                                            \
          pendN[j] = ATOMIC_LD_RLX(upN + (size_t)j * size);                    \
      }                                                                        \
    }                                                                          \
                                                                               \
    /* ---- prefetch consumer progress (non-blocking) ---- */                  \
    int pfCons = -0x40000000;                                                  \
    const int need = (bi - slotsB + 1) * B;                                    \
    if (hasCons && bi >= slotsB && cachedCons < need) {                        \
      int v0 = ATOMIC_LD_RLX(&prog[c0i]);                                      \
      int v1 = (c1i == c0i) ? v0 : ATOMIC_LD_RLX(&prog[c1i]);                  \
      pfCons = (v0 < v1) ? v0 : v1;                                            \
    }                                                                          \
                                                                               \
    /* ---- verify current-batch tags: parallel reload fast path ---- */       \
    if (hasProd && validT) {                                                   \
      const unsigned long long* upC =                                          \
          ringUp + (size_t)(bi & sBm1) * upSlotSz + e;                         \
      unsigned mism = 0;                                                       \
      _Pragma("unroll")                                                        \
      for (int j = 0; j < B; ++j)                                              \
        mism |= ((unsigned)(pendC[j] >> 32) ^ (unsigned)(tb + j + 1));         \
      if (mism) {                                                              \
        _Pragma("unroll")                                                      \
        for (int j = 0; j < B; ++j)                                            \
          pendC[j] = ATOMIC_LD_RLX(upC + (size_t)j * size);                    \
        _Pragma("unroll")                                                      \
        for (int j = 0; j < B; ++j) {                                          \
          const unsigned tagWant = (unsigned)(tb + j + 1);                     \
          unsigned long long v = pendC[j];                                     \
          int spin = 0;                                                        \
          while ((unsigned)(v >> 32) != tagWant) {                             \
            if (((++spin) & 63) == 0) __builtin_amdgcn_s_sleep(1);             \
            v = ATOMIC_LD_RLX(upC + (size_t)j * size);                         \
          }                                                                    \
          pendC[j] = v;                                                        \
        }                                                                      \
      }                                                                        \
    }                                                                          \
                                                                               \
    /* ---- compute the B steps ---- */                                        \
    float qs[B];                                                               \
    _Pragma("unroll")                                                          \
    for (int j = 0; j < B; ++j) {                                              \
      float inflow = latC[j];                                                  \
      if (hasProd && validT)                                                   \
        inflow += __uint_as_float((unsigned)pendC[j]);                         \
                                                                               \
      float q = Q;                                                             \
      const float ti  = inflow;                                                \
      const float t13 = ti * (1.0f/3.0f);                                      \
      const float t23 = ti * (2.0f/3.0f);                                      \
      const float dti = (2.0f * DT_SUB_F) * ti;                                \
      {   /* substep 0: io = Ip */                                             \
        const float io = Ip;                                                   \
        float Qref = fmaxf(fmaf(io + q, 1.0f/3.0f, t13), EPS_F);               \
        float lq   = FAST_LOG2(Qref);                                          \
        float K2   = FAST_EXP2(fmaf(eK, lq, cK2));                             \
        float t    = FAST_EXP2(fmaf(et, lq, ct));                              \
        float X    = fmaxf(0.5f - t, 0.0f);                                    \
        float KX2  = K2 * X;                                                   \
        float A    = K2 - KX2;                                                 \
        float rD   = FAST_RCP(A + DT_SUB_F);                                   \
        float num  = fmaf(A, q, fmaf(KX2, io - ti,                             \
                           DT_SUB_F * ((ti + io) - q)));                       \
        q = fmaxf(num * rD, 0.0f);                                             \
      }                                                                        \
      _Pragma("unroll")                                                        \
      for (int s = 1; s < 4; ++s) {   /* substeps 1..3: io == inflow */        \
        float Qref = fmaxf(fmaf(q, 1.0f/3.0f, t23), EPS_F);                    \
        float lq   = FAST_LOG2(Qref);                                          \
        float K2   = FAST_EXP2(fmaf(eK, lq, cK2));                             \
        float t    = FAST_EXP2(fmaf(et, lq, ct));                              \
        float X    = fmaxf(0.5f - t, 0.0f);                                    \
        float A    = K2 - K2 * X;                                              \
        float rD   = FAST_RCP(A + DT_SUB_F);                                   \
        float num  = fmaf(A, q, fmaf(-DT_SUB_F, q, dti)); /* +DT*(2ti-q) */    \
        q = fmaxf(num * rD, 0.0f);                                             \
      }                                                                        \
      Q = q; Ip = inflow;                                                      \
                                                                               \
      if (hasCons) qs[j] = pair_sum(q);        /* DPP, no LDS */               \
      else if (tid == 0) out[tb + j] = q;                                      \
    }                                                                          \
                                                                               \
    /* ---- back-pressure, then store the batch ---- */                        \
    if (hasCons) {                                                             \
      if (bi >= slotsB && cachedCons < need) {                                 \
        if (pfCons >= need) {                                                  \
          cachedCons = pfCons;                                                 \
        } else {                                                               \
          int spin = 0;                                                        \
          for (;;) {                                                           \
            int v0 = ATOMIC_LD_RLX(&prog[c0i]);                                \
            int v1 = (c1i == c0i) ? v0 : ATOMIC_LD_RLX(&prog[c1i]);            \
            int m  = (v0 < v1) ? v0 : v1;                                      \
            if (m >= need) { cachedCons = m; break; }                          \
            if (((++spin) & 63) == 0) __builtin_amdgcn_s_sleep(1);             \
          }                                                                    \
        }                                                                      \
      }                                                                        \
      if (validT && ((tid & 1) == 0)) {                                        \
        unsigned long long* st =                                               \
            ringMy + (size_t)(bi & sBm1) * mySlotSz + (e >> 1);                \
        _Pragma("unroll")                                                      \
        for (int j = 0; j < B; ++j) {                                          \
          unsigned long long v =                                               \
              ((unsigned long long)(unsigned)(tb + j + 1) << 32) |             \
              (unsigned long long)__float_as_uint(qs[j]);                      \
          ATOMIC_ST_RLX(st + (size_t)j * halfSize, v);                         \
        }                                                                      \
      }                                                                        \
    }                                                                          \
                                                                               \
    /* ---- publish per-wave consumed progress ---- */                         \
    if (waveLead) {                                                            \
      int pubv = tb + B;                                                       \
      __asm__ volatile("" : "+v"(pubv) : "v"(Q));  /* orders after reads */    \
      ATOMIC_ST_RLX(&prog[myCtr], pubv);                                       \
    }                                                                          \
  }

template<int B>
__global__ __launch_bounds__(256, 1)
void mc_route_pipe12(const float* __restrict__ lat,
                     const float* __restrict__ logn,
                     const float* __restrict__ len,
                     const float* __restrict__ slope,
                     const float* __restrict__ wcoef,
                     const float* __restrict__ wexp,
                     const float* __restrict__ dcoef,
                     const float* __restrict__ dexp,
                     float* __restrict__ out,
                     int* __restrict__ prog,
                     unsigned long long* __restrict__ ring,
                     int slotsB)
{
    const int bid = blockIdx.x;
    const int tid = threadIdx.x;
    const int NB  = T_STEPS / B;

    int lvl = 0;
#pragma unroll
    for (int l = 1; l < N_LEVELS; ++l)
        if (bid >= kBlkStart[l]) lvl = l;

    const int  bl     = bid - kBlkStart[lvl];
    const int  epb    = kEpb[lvl];
    const int  size   = kSize[lvl];
    const bool validT = (tid < epb);
    const int  e      = bl * epb + (validT ? tid : (epb - 1));
    const int  rr     = kOffL[lvl] + e;

    // -------- per-reach constants (chain-fused form, v5-verified) ----------
    const float dx      = len[rr];
    const float S       = slope[rr];
    const float sqrtS_n = sqrtf(S) * expf(-logn[rr]);        // sqrt(S)/n
    const float de23    = 0.66666667f * dexp[rr];
    const float l2dc    = log2f(dcoef[rr]);
    const float l2base  = log2f(0.6f / sqrtS_n) - 0.66666667f * l2dc;
    const float eK      = -de23;
    const float cK2     = log2f(2.0f * dx) + l2base;
    const float et      = 1.0f - de23 - wexp[rr];
    const float ct      = log2f(0.5f / (S * dx)) + l2base - log2f(wcoef[rr]);

    // -------- pipeline wiring ----------------------------------------------
    const bool hasProd = (lvl > 0);
    const bool hasCons = (lvl < N_LEVELS - 1);
    const int  SBB     = slotsB * B;
    const int  sBm1    = slotsB - 1;
    const unsigned long long* ringUp = hasProd ? ring + (size_t)kOffH[lvl-1] * SBB : ring;
    unsigned long long*       ringMy = hasCons ? ring + (size_t)kOffH[lvl]   * SBB : ring;
    const int halfSize = size >> 1;
    const int upSlotSz = size * B;
    const int mySlotSz = halfSize * B;

    int c0i = 0, c1i = 0;
    if (hasCons) {
        const int ceLo = (bl * epb) >> 1;
        const int ceHi = ((bl + 1) * epb - 1) >> 1;
        const int epbN = kEpb[lvl+1];
        const int cb   = kBlkStart[lvl+1] + ceLo / epbN;
        const int le0  = ceLo - (ceLo / epbN) * epbN;
        const int le1  = ceHi - (ceHi / epbN) * epbN;
        c0i = (cb * 4 + (le0 >> 6)) * CTR_STRIDE;
        c1i = (cb * 4 + (le1 >> 6)) * CTR_STRIDE;
    }
    const int  myCtr    = (bid * 4 + (tid >> 6)) * CTR_STRIDE;
    const bool waveLead = ((tid & 63) == 0);

    float Q = 0.0f, Ip = 0.0f;
    int cachedCons = -0x40000000;

    float latA[B], latB[B];
    unsigned long long pendA[B], pendB[B];

    // -------- prologue: load batch 0 into bank A ---------------------------
#pragma unroll
    for (int j = 0; j < B; ++j)
        latA[j] = lat[(size_t)j * NR_TOTAL + rr];
    if (hasProd && validT) {
#pragma unroll
        for (int j = 0; j < B; ++j)
            pendA[j] = ATOMIC_LD_RLX(ringUp + (size_t)j * size + e);
    }

    // 2x-unrolled batch loop, ping-pong banks (no swap movs, no pointers)
    for (int bb = 0; bb < NB; bb += 2) {
        MC_BODY(bb,     latA, pendA, latB, pendB);
        MC_BODY(bb + 1, latB, pendB, latA, pendA);
    }
}

extern "C" void kernel_launch(void* const* d_in, const int* in_sizes, int n_in,
                              void* d_out, int out_size, void* d_ws, size_t ws_size,
                              hipStream_t stream) {
    const float* lat   = (const float*)d_in[0];
    const float* logn  = (const float*)d_in[1];
    const float* len   = (const float*)d_in[2];
    const float* slope = (const float*)d_in[3];
    const float* wc    = (const float*)d_in[4];
    const float* we    = (const float*)d_in[5];
    const float* dc    = (const float*)d_in[6];
    const float* de    = (const float*)d_in[7];
    float* out = (float*)d_out;

    int* prog = (int*)d_ws;
    unsigned long long* ring = (unsigned long long*)((char*)d_ws + RING_BYTE_OFF);

    auto needBytes = [](int Bv, int Sv) {
        return (size_t)RING_BYTE_OFF + (size_t)8191 * 8 * Bv * Sv;
    };

    if (needBytes(16, 8) <= ws_size) {
        mc_route_pipe12<16><<<NBLOCKS, 256, 0, stream>>>(lat, logn, len, slope, wc, we, dc, de,
                                                         out, prog, ring, 8);
    } else if (needBytes(16, 4) <= ws_size) {
        mc_route_pipe12<16><<<NBLOCKS, 256, 0, stream>>>(lat, logn, len, slope, wc, we, dc, de,
                                                         out, prog, ring, 4);
    } else if (needBytes(16, 2) <= ws_size) {
        mc_route_pipe12<16><<<NBLOCKS, 256, 0, stream>>>(lat, logn, len, slope, wc, we, dc, de,
                                                         out, prog, ring, 2);
    } else if (needBytes(8, 4) <= ws_size) {
        mc_route_pipe12<8><<<NBLOCKS, 256, 0, stream>>>(lat, logn, len, slope, wc, we, dc, de,
                                                        out, prog, ring, 4);
    } else {
        mc_route_pipe12<8><<<NBLOCKS, 256, 0, stream>>>(lat, logn, len, slope, wc, we, dc, de,
                                                        out, prog, ring, 2);
    }
}

// Round 3
// 711.124 us; speedup vs baseline: 1.1362x; 1.1362x over previous
//
#include <hip/hip_runtime.h>
#include <math.h>
#include <stdint.h>

// ---------------------------------------------------------------------------
// Muskingum-Cunge tree routing, spatially-pipelined persistent kernel, v13.
//
// v12 post-mortem: scratch theory wrong (VGPR 80->92, dur neutral). Revised
// regime read: VALUBusy ~50% on active CUs at 775cy/step => ~390 issue-cy/step
// vs ~250 for the math alone; the prefetch/store/tag glue executes SERIALLY
// in its own small basic blocks (MachineScheduler is per-BB; the body was
// chopped up by bi+1<NB / hasProd&&validT / per-iteration hasCons branches),
// instead of filling the ~50% stall slots inside the dependent math chain.
//
// v13 change (math bit-identical):
//   ONE giant branchless BB per body = [16 unconditional clamped lat loads +
//   16 math steps + pair_sum + uniform select into qs[]]. Upstream add is
//   branchless via prodMask (pend banks zero-init for level 0; no validT
//   divergence -- invalid lanes compute on clamped duplicates, never stored).
//   Pend prefetch + tag scan stay at the head under one uniform if(hasProd).
//   All stores in a compact tail. Scheduler can now hoist load issue and
//   address math into the chain's stall slots.
//
// Protocol unchanged: per-level persistent blocks, batched ring handoff,
// tagged 8-byte relaxed agent-scope atomics, flat mismatch scan + parallel
// reload + spin backstop, per-wave progress counters, DPP pair_sum,
// 2x-unrolled ping-pong batch loop.
// ---------------------------------------------------------------------------

#define N_LEVELS   14
#define T_STEPS    2048
#define NR_TOTAL   16383
#define DT_SUB_F   21600.0f
#define EPS_F      1e-6f
#define NBLOCKS    71
#define CTR_STRIDE 8             // ints per wave counter (32 B apart)
#define RING_BYTE_OFF 16384

__device__ __constant__ int kSize[N_LEVELS] = {8192,4096,2048,1024,512,256,128,64,32,16,8,4,2,1};
__device__ __constant__ int kEpb [N_LEVELS] = {256,256,256,256,256,256,128,64,32,16,8,4,2,1};
__device__ __constant__ int kBlkStart[N_LEVELS+1] = {0,32,48,56,60,62,63,64,65,66,67,68,69,70,71};
__device__ __constant__ int kOffL[N_LEVELS] = {0,8192,12288,14336,15360,15872,16128,16256,16320,16352,16368,16376,16380,16382};
// pair-sum entries before level l
__device__ __constant__ int kOffH[N_LEVELS-1] = {0,4096,6144,7168,7680,7936,8064,8128,8160,8176,8184,8188,8190};

#if __has_builtin(__builtin_amdgcn_exp2f)
#define FAST_EXP2(x) __builtin_amdgcn_exp2f(x)
#else
#define FAST_EXP2(x) exp2f(x)
#endif
#if __has_builtin(__builtin_amdgcn_logf)
#define FAST_LOG2(x) __builtin_amdgcn_logf(x)
#else
#define FAST_LOG2(x) log2f(x)
#endif
#if __has_builtin(__builtin_amdgcn_rcpf)
#define FAST_RCP(x) __builtin_amdgcn_rcpf(x)
#else
#define FAST_RCP(x) (1.0f/(x))
#endif

// pair sum of lanes (2k,2k+1) via DPP quad_perm [1,0,3,2]: pure VALU, no LDS.
__device__ __forceinline__ float pair_sum(float x) {
    int yi = __builtin_amdgcn_update_dpp(0, __float_as_int(x),
                                         0xB1 /*quad_perm 1,0,3,2*/,
                                         0xF, 0xF, true);
    return x + __int_as_float(yi);
}

#define ATOMIC_LD_RLX(p)   __hip_atomic_load((p), __ATOMIC_RELAXED, __HIP_MEMORY_SCOPE_AGENT)
#define ATOMIC_ST_RLX(p,v) __hip_atomic_store((p), (v), __ATOMIC_RELAXED, __HIP_MEMORY_SCOPE_AGENT)

// ---------------------------------------------------------------------------
// One batch body (textual macro; banks substitute as plain array names).
// ---------------------------------------------------------------------------
#define MC_BODY(BI, latC, pendC, latN, pendN)                                  \
  {                                                                            \
    const int bi = (BI);                                                       \
    const int tb = bi * B;                                                     \
    /* clamped next-batch time base: last body harmlessly re-reads last batch*/\
    const int tbn = (tb + B < T_STEPS) ? (tb + B) : (T_STEPS - B);             \
                                                                               \
    /* ---- poll consumer progress early (non-blocking) ---- */                \
    int pfCons = -0x40000000;                                                  \
    const int need = (bi - slotsB + 1) * B;                                    \
    if (hasCons && bi >= slotsB && cachedCons < need) {                        \
      int v0 = ATOMIC_LD_RLX(&prog[c0i]);                                      \
      int v1 = (c1i == c0i) ? v0 : ATOMIC_LD_RLX(&prog[c1i]);                  \
      pfCons = (v0 < v1) ? v0 : v1;                                            \
    }                                                                          \
                                                                               \
    /* ---- ring: prefetch NEXT batch + verify CURRENT batch tags ---- */      \
    if (hasProd) {                                                             \
      const unsigned long long* upN =                                          \
          ringUp + (size_t)((bi + 1) & sBm1) * upSlotSz + e;                   \
      _Pragma("unroll")                                                        \
      for (int j = 0; j < B; ++j)                                              \
        pendN[j] = ATOMIC_LD_RLX(upN + (size_t)j * size);                      \
      const unsigned long long* upC =                                          \
          ringUp + (size_t)(bi & sBm1) * upSlotSz + e;                         \
      unsigned mism = 0;                                                       \
      _Pragma("unroll")                                                        \
      for (int j = 0; j < B; ++j)                                              \
        mism |= ((unsigned)(pendC[j] >> 32) ^ (unsigned)(tb + j + 1));         \
      if (mism) {                                                              \
        _Pragma("unroll")                                                      \
        for (int j = 0; j < B; ++j)                                            \
          pendC[j] = ATOMIC_LD_RLX(upC + (size_t)j * size);                    \
        _Pragma("unroll")                                                      \
        for (int j = 0; j < B; ++j) {                                          \
          const unsigned tagWant = (unsigned)(tb + j + 1);                     \
          unsigned long long v = pendC[j];                                     \
          int spin = 0;                                                        \
          while ((unsigned)(v >> 32) != tagWant) {                             \
            if (((++spin) & 63) == 0) __builtin_amdgcn_s_sleep(1);             \
            v = ATOMIC_LD_RLX(upC + (size_t)j * size);                         \
          }                                                                    \
          pendC[j] = v;                                                        \
        }                                                                      \
      }                                                                        \
    }                                                                          \
                                                                               \
    /* ================= giant branchless BB ================= */              \
    float qs[B];                                                               \
    {                                                                          \
      const size_t nbBase = (size_t)tbn * NR_TOTAL + (size_t)rr;               \
      _Pragma("unroll")                                                        \
      for (int j = 0; j < B; ++j)                                              \
        latN[j] = lat[nbBase + (size_t)j * NR_TOTAL];                          \
      _Pragma("unroll")                                                        \
      for (int j = 0; j < B; ++j) {                                            \
        float inflow = latC[j] +                                               \
            __uint_as_float((unsigned)pendC[j] & prodMask);                    \
                                                                               \
        float q = Q;                                                           \
        const float ti  = inflow;                                              \
        const float t13 = ti * (1.0f/3.0f);                                    \
        const float t23 = ti * (2.0f/3.0f);                                    \
        const float dti = (2.0f * DT_SUB_F) * ti;                              \
        {   /* substep 0: io = Ip */                                           \
          const float io = Ip;                                                 \
          float Qref = fmaxf(fmaf(io + q, 1.0f/3.0f, t13), EPS_F);             \
          float lq   = FAST_LOG2(Qref);                                        \
          float K2   = FAST_EXP2(fmaf(eK, lq, cK2));                           \
          float t    = FAST_EXP2(fmaf(et, lq, ct));                            \
          float X    = fmaxf(0.5f - t, 0.0f);                                  \
          float KX2  = K2 * X;                                                 \
          float A    = K2 - KX2;                                               \
          float rD   = FAST_RCP(A + DT_SUB_F);                                 \
          float num  = fmaf(A, q, fmaf(KX2, io - ti,                           \
                             DT_SUB_F * ((ti + io) - q)));                     \
          q = fmaxf(num * rD, 0.0f);                                           \
        }                                                                      \
        _Pragma("unroll")                                                      \
        for (int s = 1; s < 4; ++s) {   /* substeps 1..3: io == inflow */      \
          float Qref = fmaxf(fmaf(q, 1.0f/3.0f, t23), EPS_F);                  \
          float lq   = FAST_LOG2(Qref);                                        \
          float K2   = FAST_EXP2(fmaf(eK, lq, cK2));                           \
          float t    = FAST_EXP2(fmaf(et, lq, ct));                            \
          float X    = fmaxf(0.5f - t, 0.0f);                                  \
          float A    = K2 - K2 * X;                                            \
          float rD   = FAST_RCP(A + DT_SUB_F);                                 \
          float num  = fmaf(A, q, fmaf(-DT_SUB_F, q, dti)); /* +DT*(2ti-q) */  \
          q = fmaxf(num * rD, 0.0f);                                           \
        }                                                                      \
        Q = q; Ip = inflow;                                                    \
                                                                               \
        float ps = pair_sum(q);          /* DPP, branchless, always */         \
        qs[j] = hasCons ? ps : q;        /* uniform select */                  \
      }                                                                        \
    }                                                                          \
    /* ================= end giant BB ================= */                     \
                                                                               \
    /* ---- back-pressure, then store the batch ---- */                        \
    if (hasCons) {                                                             \
      if (bi >= slotsB && cachedCons < need) {                                 \
        if (pfCons >= need) {                                                  \
          cachedCons = pfCons;                                                 \
        } else {                                                               \
          int spin = 0;                                                        \
          for (;;) {                                                           \
            int v0 = ATOMIC_LD_RLX(&prog[c0i]);                                \
            int v1 = (c1i == c0i) ? v0 : ATOMIC_LD_RLX(&prog[c1i]);            \
            int m  = (v0 < v1) ? v0 : v1;                                      \
            if (m >= need) { cachedCons = m; break; }                          \
            if (((++spin) & 63) == 0) __builtin_amdgcn_s_sleep(1);             \
          }                                                                    \
        }                                                                      \
      }                                                                        \
      if (validT && ((tid & 1) == 0)) {                                        \
        unsigned long long* st =                                               \
            ringMy + (size_t)(bi & sBm1) * mySlotSz + (e >> 1);                \
        _Pragma("unroll")                                                      \
        for (int j = 0; j < B; ++j) {                                          \
          unsigned long long v =                                               \
              ((unsigned long long)(unsigned)(tb + j + 1) << 32) |             \
              (unsigned long long)__float_as_uint(qs[j]);                      \
          ATOMIC_ST_RLX(st + (size_t)j * halfSize, v);                         \
        }                                                                      \
      }                                                                        \
    } else if (tid == 0) {                                                     \
      _Pragma("unroll")                                                        \
      for (int j = 0; j < B; ++j)                                              \
        out[tb + j] = qs[j];                                                   \
    }                                                                          \
                                                                               \
    /* ---- publish per-wave consumed progress ---- */                         \
    if (waveLead) {                                                            \
      int pubv = tb + B;                                                       \
      __asm__ volatile("" : "+v"(pubv) : "v"(Q));  /* orders after reads */    \
      ATOMIC_ST_RLX(&prog[myCtr], pubv);                                       \
    }                                                                          \
  }

template<int B>
__global__ __launch_bounds__(256, 1)
void mc_route_pipe13(const float* __restrict__ lat,
                     const float* __restrict__ logn,
                     const float* __restrict__ len,
                     const float* __restrict__ slope,
                     const float* __restrict__ wcoef,
                     const float* __restrict__ wexp,
                     const float* __restrict__ dcoef,
                     const float* __restrict__ dexp,
                     float* __restrict__ out,
                     int* __restrict__ prog,
                     unsigned long long* __restrict__ ring,
                     int slotsB)
{
    const int bid = blockIdx.x;
    const int tid = threadIdx.x;
    const int NB  = T_STEPS / B;
    (void)NB;

    int lvl = 0;
#pragma unroll
    for (int l = 1; l < N_LEVELS; ++l)
        if (bid >= kBlkStart[l]) lvl = l;

    const int  bl     = bid - kBlkStart[lvl];
    const int  epb    = kEpb[lvl];
    const int  size   = kSize[lvl];
    const bool validT = (tid < epb);
    const int  e      = bl * epb + (validT ? tid : (epb - 1));
    const int  rr     = kOffL[lvl] + e;

    // -------- per-reach constants (chain-fused form, v5-verified) ----------
    const float dx      = len[rr];
    const float S       = slope[rr];
    const float sqrtS_n = sqrtf(S) * expf(-logn[rr]);        // sqrt(S)/n
    const float de23    = 0.66666667f * dexp[rr];
    const float l2dc    = log2f(dcoef[rr]);
    const float l2base  = log2f(0.6f / sqrtS_n) - 0.66666667f * l2dc;
    const float eK      = -de23;
    const float cK2     = log2f(2.0f * dx) + l2base;
    const float et      = 1.0f - de23 - wexp[rr];
    const float ct      = log2f(0.5f / (S * dx)) + l2base - log2f(wcoef[rr]);

    // -------- pipeline wiring ----------------------------------------------
    const bool hasProd = (lvl > 0);
    const bool hasCons = (lvl < N_LEVELS - 1);
    const unsigned prodMask = hasProd ? 0xFFFFFFFFu : 0u;
    const int  SBB     = slotsB * B;
    const int  sBm1    = slotsB - 1;
    const unsigned long long* ringUp = hasProd ? ring + (size_t)kOffH[lvl-1] * SBB : ring;
    unsigned long long*       ringMy = hasCons ? ring + (size_t)kOffH[lvl]   * SBB : ring;
    const int halfSize = size >> 1;
    const int upSlotSz = size * B;
    const int mySlotSz = halfSize * B;

    int c0i = 0, c1i = 0;
    if (hasCons) {
        const int ceLo = (bl * epb) >> 1;
        const int ceHi = ((bl + 1) * epb - 1) >> 1;
        const int epbN = kEpb[lvl+1];
        const int cb   = kBlkStart[lvl+1] + ceLo / epbN;
        const int le0  = ceLo - (ceLo / epbN) * epbN;
        const int le1  = ceHi - (ceHi / epbN) * epbN;
        c0i = (cb * 4 + (le0 >> 6)) * CTR_STRIDE;
        c1i = (cb * 4 + (le1 >> 6)) * CTR_STRIDE;
    }
    const int  myCtr    = (bid * 4 + (tid >> 6)) * CTR_STRIDE;
    const bool waveLead = ((tid & 63) == 0);

    float Q = 0.0f, Ip = 0.0f;
    int cachedCons = -0x40000000;

    float latA[B], latB[B];
    unsigned long long pendA[B], pendB[B];

    // -------- prologue: load batch 0 into bank A ---------------------------
#pragma unroll
    for (int j = 0; j < B; ++j)
        latA[j] = lat[(size_t)j * NR_TOTAL + rr];
    if (hasProd) {
#pragma unroll
        for (int j = 0; j < B; ++j)
            pendA[j] = ATOMIC_LD_RLX(ringUp + (size_t)j * size + e);
    } else {
#pragma unroll
        for (int j = 0; j < B; ++j) { pendA[j] = 0; pendB[j] = 0; }
    }

    // 2x-unrolled batch loop, ping-pong banks (no swap movs, no pointers)
    for (int bb = 0; bb < T_STEPS / B; bb += 2) {
        MC_BODY(bb,     latA, pendA, latB, pendB);
        MC_BODY(bb + 1, latB, pendB, latA, pendA);
    }
}

extern "C" void kernel_launch(void* const* d_in, const int* in_sizes, int n_in,
                              void* d_out, int out_size, void* d_ws, size_t ws_size,
                              hipStream_t stream) {
    const float* lat   = (const float*)d_in[0];
    const float* logn  = (const float*)d_in[1];
    const float* len   = (const float*)d_in[2];
    const float* slope = (const float*)d_in[3];
    const float* wc    = (const float*)d_in[4];
    const float* we    = (const float*)d_in[5];
    const float* dc    = (const float*)d_in[6];
    const float* de    = (const float*)d_in[7];
    float* out = (float*)d_out;

    int* prog = (int*)d_ws;
    unsigned long long* ring = (unsigned long long*)((char*)d_ws + RING_BYTE_OFF);

    auto needBytes = [](int Bv, int Sv) {
        return (size_t)RING_BYTE_OFF + (size_t)8191 * 8 * Bv * Sv;
    };

    if (needBytes(16, 8) <= ws_size) {
        mc_route_pipe13<16><<<NBLOCKS, 256, 0, stream>>>(lat, logn, len, slope, wc, we, dc, de,
                                                         out, prog, ring, 8);
    } else if (needBytes(16, 4) <= ws_size) {
        mc_route_pipe13<16><<<NBLOCKS, 256, 0, stream>>>(lat, logn, len, slope, wc, we, dc, de,
                                                         out, prog, ring, 4);
    } else if (needBytes(16, 2) <= ws_size) {
        mc_route_pipe13<16><<<NBLOCKS, 256, 0, stream>>>(lat, logn, len, slope, wc, we, dc, de,
                                                         out, prog, ring, 2);
    } else if (needBytes(8, 4) <= ws_size) {
        mc_route_pipe13<8><<<NBLOCKS, 256, 0, stream>>>(lat, logn, len, slope, wc, we, dc, de,
                                                        out, prog, ring, 4);
    } else {
        mc_route_pipe13<8><<<NBLOCKS, 256, 0, stream>>>(lat, logn, len, slope, wc, we, dc, de,
                                                        out, prog, ring, 2);
    }
}

// Round 4
// 696.644 us; speedup vs baseline: 1.1598x; 1.0208x over previous
//
#include <hip/hip_runtime.h>
#include <math.h>
#include <stdint.h>

// ---------------------------------------------------------------------------
// Muskingum-Cunge tree routing, spatially-pipelined persistent kernel, v14.
//
// v13 (giant branchless BB) verified: 666 -> 567 us, VALUBusy 13.9 -> 16.6%.
// v14 theory: the remaining per-batch glue is the ring reload round-trip.
// The consumer prefetched batch bi's ring data at the HEAD of body bi-1 --
// structurally BEFORE the producer stores batch bi (for any inter-level lag
// < C_batch), so the prefetch is always stale and every batch pays one MALL
// round-trip (~900cy ~= 56cy/step) before math. Availability waits get
// absorbed into the self-adjusting inter-level lag; reload cost does not.
//
// v14 change (math bit-identical):
//   (1) next-batch ring prefetch moved from body head to MID-BODY (between
//       math steps B/2-1 and B/2): issued ~C/2 before use -> lag self-adjusts
//       so the data is fresh at issue, and the flight hides under 8 steps of
//       math. Steady-state head scan passes with zero reloads. Unconditional
//       (level-0 reads harmless in-bounds garbage, masked by prodMask) so the
//       math mega-BB is not split by a branch.
//   (2) serial per-element spin backstop -> whole-batch parallel reload +
//       rescan retry loop (one round-trip per retry instead of B).
//
// Protocol otherwise unchanged: per-level persistent blocks, batched ring
// handoff, tagged 8-byte relaxed agent-scope atomics, per-wave progress
// counters, DPP pair_sum, 2x-unrolled ping-pong batch loop.
// ---------------------------------------------------------------------------

#define N_LEVELS   14
#define T_STEPS    2048
#define NR_TOTAL   16383
#define DT_SUB_F   21600.0f
#define EPS_F      1e-6f
#define NBLOCKS    71
#define CTR_STRIDE 8             // ints per wave counter (32 B apart)
#define RING_BYTE_OFF 16384

__device__ __constant__ int kSize[N_LEVELS] = {8192,4096,2048,1024,512,256,128,64,32,16,8,4,2,1};
__device__ __constant__ int kEpb [N_LEVELS] = {256,256,256,256,256,256,128,64,32,16,8,4,2,1};
__device__ __constant__ int kBlkStart[N_LEVELS+1] = {0,32,48,56,60,62,63,64,65,66,67,68,69,70,71};
__device__ __constant__ int kOffL[N_LEVELS] = {0,8192,12288,14336,15360,15872,16128,16256,16320,16352,16368,16376,16380,16382};
// pair-sum entries before level l
__device__ __constant__ int kOffH[N_LEVELS-1] = {0,4096,6144,7168,7680,7936,8064,8128,8160,8176,8184,8188,8190};

#if __has_builtin(__builtin_amdgcn_exp2f)
#define FAST_EXP2(x) __builtin_amdgcn_exp2f(x)
#else
#define FAST_EXP2(x) exp2f(x)
#endif
#if __has_builtin(__builtin_amdgcn_logf)
#define FAST_LOG2(x) __builtin_amdgcn_logf(x)
#else
#define FAST_LOG2(x) log2f(x)
#endif
#if __has_builtin(__builtin_amdgcn_rcpf)
#define FAST_RCP(x) __builtin_amdgcn_rcpf(x)
#else
#define FAST_RCP(x) (1.0f/(x))
#endif

// pair sum of lanes (2k,2k+1) via DPP quad_perm [1,0,3,2]: pure VALU, no LDS.
__device__ __forceinline__ float pair_sum(float x) {
    int yi = __builtin_amdgcn_update_dpp(0, __float_as_int(x),
                                         0xB1 /*quad_perm 1,0,3,2*/,
                                         0xF, 0xF, true);
    return x + __int_as_float(yi);
}

#define ATOMIC_LD_RLX(p)   __hip_atomic_load((p), __ATOMIC_RELAXED, __HIP_MEMORY_SCOPE_AGENT)
#define ATOMIC_ST_RLX(p,v) __hip_atomic_store((p), (v), __ATOMIC_RELAXED, __HIP_MEMORY_SCOPE_AGENT)

// One math step (fully unrolled, constant j). References enclosing-scope
// Q, Ip, prodMask, hasCons, per-reach constants; writes qs[j].
#define MC_MATH_LOOP(J0, J1, latC, pendC)                                      \
      _Pragma("unroll")                                                        \
      for (int j = (J0); j < (J1); ++j) {                                      \
        float inflow = latC[j] +                                               \
            __uint_as_float((unsigned)pendC[j] & prodMask);                    \
                                                                               \
        float q = Q;                                                           \
        const float ti  = inflow;                                              \
        const float t13 = ti * (1.0f/3.0f);                                    \
        const float t23 = ti * (2.0f/3.0f);                                    \
        const float dti = (2.0f * DT_SUB_F) * ti;                              \
        {   /* substep 0: io = Ip */                                           \
          const float io = Ip;                                                 \
          float Qref = fmaxf(fmaf(io + q, 1.0f/3.0f, t13), EPS_F);             \
          float lq   = FAST_LOG2(Qref);                                        \
          float K2   = FAST_EXP2(fmaf(eK, lq, cK2));                           \
          float t    = FAST_EXP2(fmaf(et, lq, ct));                            \
          float X    = fmaxf(0.5f - t, 0.0f);                                  \
          float KX2  = K2 * X;                                                 \
          float A    = K2 - KX2;                                               \
          float rD   = FAST_RCP(A + DT_SUB_F);                                 \
          float num  = fmaf(A, q, fmaf(KX2, io - ti,                           \
                             DT_SUB_F * ((ti + io) - q)));                     \
          q = fmaxf(num * rD, 0.0f);                                           \
        }                                                                      \
        _Pragma("unroll")                                                      \
        for (int s = 1; s < 4; ++s) {   /* substeps 1..3: io == inflow */      \
          float Qref = fmaxf(fmaf(q, 1.0f/3.0f, t23), EPS_F);                  \
          float lq   = FAST_LOG2(Qref);                                        \
          float K2   = FAST_EXP2(fmaf(eK, lq, cK2));                           \
          float t    = FAST_EXP2(fmaf(et, lq, ct));                            \
          float X    = fmaxf(0.5f - t, 0.0f);                                  \
          float A    = K2 - K2 * X;                                            \
          float rD   = FAST_RCP(A + DT_SUB_F);                                 \
          float num  = fmaf(A, q, fmaf(-DT_SUB_F, q, dti)); /* +DT*(2ti-q) */  \
          q = fmaxf(num * rD, 0.0f);                                           \
        }                                                                      \
        Q = q; Ip = inflow;                                                    \
                                                                               \
        float ps = pair_sum(q);          /* DPP, branchless, always */         \
        qs[j] = hasCons ? ps : q;        /* uniform select */                  \
      }

// ---------------------------------------------------------------------------
// One batch body (textual macro; banks substitute as plain array names).
// ---------------------------------------------------------------------------
#define MC_BODY(BI, latC, pendC, latN, pendN)                                  \
  {                                                                            \
    const int bi = (BI);                                                       \
    const int tb = bi * B;                                                     \
    /* clamped next-batch time base: last body harmlessly re-reads last batch*/\
    const int tbn = (tb + B < T_STEPS) ? (tb + B) : (T_STEPS - B);             \
                                                                               \
    /* ---- poll consumer progress early (non-blocking) ---- */                \
    int pfCons = -0x40000000;                                                  \
    const int need = (bi - slotsB + 1) * B;                                    \
    if (hasCons && bi >= slotsB && cachedCons < need) {                        \
      int v0 = ATOMIC_LD_RLX(&prog[c0i]);                                      \
      int v1 = (c1i == c0i) ? v0 : ATOMIC_LD_RLX(&prog[c1i]);                  \
      pfCons = (v0 < v1) ? v0 : v1;                                            \
    }                                                                          \
                                                                               \
    /* ---- verify CURRENT batch tags (prefetched mid-previous body) ----- */  \
    /* Steady state: fresh -> scan passes, zero reloads. Backstop: whole- */   \
    /* batch parallel reload + rescan (one round-trip per retry).         */   \
    if (hasProd) {                                                             \
      const unsigned long long* upC =                                          \
          ringUp + (size_t)(bi & sBm1) * upSlotSz + e;                         \
      unsigned mism = 0;                                                       \
      _Pragma("unroll")                                                        \
      for (int j = 0; j < B; ++j)                                              \
        mism |= ((unsigned)(pendC[j] >> 32) ^ (unsigned)(tb + j + 1));         \
      int spin = 0;                                                            \
      while (__builtin_expect(mism != 0u, 0)) {                                \
        _Pragma("unroll")                                                      \
        for (int j = 0; j < B; ++j)                                            \
          pendC[j] = ATOMIC_LD_RLX(upC + (size_t)j * size);                    \
        mism = 0;                                                              \
        _Pragma("unroll")                                                      \
        for (int j = 0; j < B; ++j)                                            \
          mism |= ((unsigned)(pendC[j] >> 32) ^ (unsigned)(tb + j + 1));       \
        if (mism && (((++spin) & 15) == 0)) __builtin_amdgcn_s_sleep(1);       \
      }                                                                        \
    }                                                                          \
                                                                               \
    /* ================= giant branchless BB, half 0 ================= */      \
    float qs[B];                                                               \
    {                                                                          \
      const size_t nbBase = (size_t)tbn * NR_TOTAL + (size_t)rr;               \
      _Pragma("unroll")                                                        \
      for (int j = 0; j < B; ++j)                                              \
        latN[j] = lat[nbBase + (size_t)j * NR_TOTAL];                          \
      MC_MATH_LOOP(0, B/2, latC, pendC)                                        \
                                                                               \
      /* ---- mid-body: prefetch NEXT batch ring (fresh in steady state; */    \
      /* ~B/2 steps of math ahead of use covers the MALL flight).        */    \
      /* Unconditional: level-0 reads are harmless in-bounds garbage,    */    \
      /* masked by prodMask; keeps this whole region one BB.             */    \
      {                                                                        \
        const unsigned long long* upN =                                        \
            ringUp + (size_t)((bi + 1) & sBm1) * upSlotSz + e;                 \
        _Pragma("unroll")                                                      \
        for (int j = 0; j < B; ++j)                                            \
          pendN[j] = ATOMIC_LD_RLX(upN + (size_t)j * size);                    \
      }                                                                        \
                                                                               \
      MC_MATH_LOOP(B/2, B, latC, pendC)                                        \
    }                                                                          \
    /* ================= end giant BB ================= */                     \
                                                                               \
    /* ---- back-pressure, then store the batch ---- */                        \
    if (hasCons) {                                                             \
      if (bi >= slotsB && cachedCons < need) {                                 \
        if (pfCons >= need) {                                                  \
          cachedCons = pfCons;                                                 \
        } else {                                                               \
          int spin = 0;                                                        \
          for (;;) {                                                           \
            int v0 = ATOMIC_LD_RLX(&prog[c0i]);                                \
            int v1 = (c1i == c0i) ? v0 : ATOMIC_LD_RLX(&prog[c1i]);            \
            int m  = (v0 < v1) ? v0 : v1;                                      \
            if (m >= need) { cachedCons = m; break; }                          \
            if (((++spin) & 63) == 0) __builtin_amdgcn_s_sleep(1);             \
          }                                                                    \
        }                                                                      \
      }                                                                        \
      if (validT && ((tid & 1) == 0)) {                                        \
        unsigned long long* st =                                               \
            ringMy + (size_t)(bi & sBm1) * mySlotSz + (e >> 1);                \
        _Pragma("unroll")                                                      \
        for (int j = 0; j < B; ++j) {                                          \
          unsigned long long v =                                               \
              ((unsigned long long)(unsigned)(tb + j + 1) << 32) |             \
              (unsigned long long)__float_as_uint(qs[j]);                      \
          ATOMIC_ST_RLX(st + (size_t)j * halfSize, v);                         \
        }                                                                      \
      }                                                                        \
    } else if (tid == 0) {                                                     \
      _Pragma("unroll")                                                        \
      for (int j = 0; j < B; ++j)                                              \
        out[tb + j] = qs[j];                                                   \
    }                                                                          \
                                                                               \
    /* ---- publish per-wave consumed progress ---- */                         \
    if (waveLead) {                                                            \
      int pubv = tb + B;                                                       \
      __asm__ volatile("" : "+v"(pubv) : "v"(Q));  /* orders after reads */    \
      ATOMIC_ST_RLX(&prog[myCtr], pubv);                                       \
    }                                                                          \
  }

template<int B>
__global__ __launch_bounds__(256, 1)
void mc_route_pipe14(const float* __restrict__ lat,
                     const float* __restrict__ logn,
                     const float* __restrict__ len,
                     const float* __restrict__ slope,
                     const float* __restrict__ wcoef,
                     const float* __restrict__ wexp,
                     const float* __restrict__ dcoef,
                     const float* __restrict__ dexp,
                     float* __restrict__ out,
                     int* __restrict__ prog,
                     unsigned long long* __restrict__ ring,
                     int slotsB)
{
    const int bid = blockIdx.x;
    const int tid = threadIdx.x;

    int lvl = 0;
#pragma unroll
    for (int l = 1; l < N_LEVELS; ++l)
        if (bid >= kBlkStart[l]) lvl = l;

    const int  bl     = bid - kBlkStart[lvl];
    const int  epb    = kEpb[lvl];
    const int  size   = kSize[lvl];
    const bool validT = (tid < epb);
    const int  e      = bl * epb + (validT ? tid : (epb - 1));
    const int  rr     = kOffL[lvl] + e;

    // -------- per-reach constants (chain-fused form, v5-verified) ----------
    const float dx      = len[rr];
    const float S       = slope[rr];
    const float sqrtS_n = sqrtf(S) * expf(-logn[rr]);        // sqrt(S)/n
    const float de23    = 0.66666667f * dexp[rr];
    const float l2dc    = log2f(dcoef[rr]);
    const float l2base  = log2f(0.6f / sqrtS_n) - 0.66666667f * l2dc;
    const float eK      = -de23;
    const float cK2     = log2f(2.0f * dx) + l2base;
    const float et      = 1.0f - de23 - wexp[rr];
    const float ct      = log2f(0.5f / (S * dx)) + l2base - log2f(wcoef[rr]);

    // -------- pipeline wiring ----------------------------------------------
    const bool hasProd = (lvl > 0);
    const bool hasCons = (lvl < N_LEVELS - 1);
    const unsigned prodMask = hasProd ? 0xFFFFFFFFu : 0u;
    const int  SBB     = slotsB * B;
    const int  sBm1    = slotsB - 1;
    const unsigned long long* ringUp = hasProd ? ring + (size_t)kOffH[lvl-1] * SBB : ring;
    unsigned long long*       ringMy = hasCons ? ring + (size_t)kOffH[lvl]   * SBB : ring;
    const int halfSize = size >> 1;
    const int upSlotSz = size * B;
    const int mySlotSz = halfSize * B;

    int c0i = 0, c1i = 0;
    if (hasCons) {
        const int ceLo = (bl * epb) >> 1;
        const int ceHi = ((bl + 1) * epb - 1) >> 1;
        const int epbN = kEpb[lvl+1];
        const int cb   = kBlkStart[lvl+1] + ceLo / epbN;
        const int le0  = ceLo - (ceLo / epbN) * epbN;
        const int le1  = ceHi - (ceHi / epbN) * epbN;
        c0i = (cb * 4 + (le0 >> 6)) * CTR_STRIDE;
        c1i = (cb * 4 + (le1 >> 6)) * CTR_STRIDE;
    }
    const int  myCtr    = (bid * 4 + (tid >> 6)) * CTR_STRIDE;
    const bool waveLead = ((tid & 63) == 0);

    float Q = 0.0f, Ip = 0.0f;
    int cachedCons = -0x40000000;

    float latA[B], latB[B];
    unsigned long long pendA[B], pendB[B];

    // -------- prologue: load batch 0 into bank A ---------------------------
#pragma unroll
    for (int j = 0; j < B; ++j)
        latA[j] = lat[(size_t)j * NR_TOTAL + rr];
    if (hasProd) {
#pragma unroll
        for (int j = 0; j < B; ++j)
            pendA[j] = ATOMIC_LD_RLX(ringUp + (size_t)j * size + e);
    } else {
#pragma unroll
        for (int j = 0; j < B; ++j) { pendA[j] = 0; pendB[j] = 0; }
    }

    // 2x-unrolled batch loop, ping-pong banks (no swap movs, no pointers)
    for (int bb = 0; bb < T_STEPS / B; bb += 2) {
        MC_BODY(bb,     latA, pendA, latB, pendB);
        MC_BODY(bb + 1, latB, pendB, latA, pendA);
    }
}

extern "C" void kernel_launch(void* const* d_in, const int* in_sizes, int n_in,
                              void* d_out, int out_size, void* d_ws, size_t ws_size,
                              hipStream_t stream) {
    const float* lat   = (const float*)d_in[0];
    const float* logn  = (const float*)d_in[1];
    const float* len   = (const float*)d_in[2];
    const float* slope = (const float*)d_in[3];
    const float* wc    = (const float*)d_in[4];
    const float* we    = (const float*)d_in[5];
    const float* dc    = (const float*)d_in[6];
    const float* de    = (const float*)d_in[7];
    float* out = (float*)d_out;

    int* prog = (int*)d_ws;
    unsigned long long* ring = (unsigned long long*)((char*)d_ws + RING_BYTE_OFF);

    auto needBytes = [](int Bv, int Sv) {
        return (size_t)RING_BYTE_OFF + (size_t)8191 * 8 * Bv * Sv;
    };

    if (needBytes(16, 8) <= ws_size) {
        mc_route_pipe14<16><<<NBLOCKS, 256, 0, stream>>>(lat, logn, len, slope, wc, we, dc, de,
                                                         out, prog, ring, 8);
    } else if (needBytes(16, 4) <= ws_size) {
        mc_route_pipe14<16><<<NBLOCKS, 256, 0, stream>>>(lat, logn, len, slope, wc, we, dc, de,
                                                         out, prog, ring, 4);
    } else if (needBytes(16, 2) <= ws_size) {
        mc_route_pipe14<16><<<NBLOCKS, 256, 0, stream>>>(lat, logn, len, slope, wc, we, dc, de,
                                                         out, prog, ring, 2);
    } else if (needBytes(8, 4) <= ws_size) {
        mc_route_pipe14<8><<<NBLOCKS, 256, 0, stream>>>(lat, logn, len, slope, wc, we, dc, de,
                                                        out, prog, ring, 4);
    } else {
        mc_route_pipe14<8><<<NBLOCKS, 256, 0, stream>>>(lat, logn, len, slope, wc, we, dc, de,
                                                        out, prog, ring, 2);
    }
}